// Round 3
// baseline (16878.235 us; speedup 1.0000x reference)
//
#include <hip/hip_runtime.h>
#include <cstdint>
#include <cstddef>

// ============================================================================
// Persistent fused 2-layer LSTM + FC for MI355X (gfx950) — Round 8:
// BARRIER-FREE DATAFLOW. R7b post-mortem: VALUBusy(1.85%) x 21.3us/round
// ~= 950 VALU cyc/CU/round == static count => clocks nominal, compute 0.4us;
// CUs wait ~48K cyc/round on the ~6-hop agent-scope sync chain (store drain,
// flag post, sweep, gen publish, gen poll, buffer_inv, staged load). Fix:
// eliminate the grid barrier entirely — h history is fully persisted (503
// slots), so per-round per-block READY FLAGS are sufficient synchronization:
//   producer: coalesced 256B record store (sc1) -> release flag[r][bk]=1
//   consumer: thread t polls flag[r-1][t] (1 thread : 1 record), copies
//             record -> LDS. 512 threads = 256 h1 + 256 h2 records.
// Chain = store + flag + poll + load (~4 hops), per-record pipelined; blocks
// free-run (no convergence). Wave0 posts h1[r] right after the L0 zone sync,
// BEFORE L1/FC -> L1/FC off the inter-round critical path. No buffer_inv
// per round -> x/weights stay cached in L2.
// MFMA layout, zone reduction, gate math, schedule (r=1..502) unchanged.
// ============================================================================

#define NBLK 256
#define NTHR 512

typedef _Float16 f16;
typedef _Float16 f16x8 __attribute__((ext_vector_type(8)));
typedef float f32x4 __attribute__((ext_vector_type(4)));
typedef unsigned long long u64;

namespace {
constexpr int kB = 32, kT = 512, kI = 256, kH = 1024, kO = 512, kTR = 500;
constexpr int kRounds = 502;
constexpr size_t kSlots = 503;
// workspace layout (bytes)
constexpr size_t kFH1Off = 0;                        // flagsH1 [503][256] u32
constexpr size_t kFH2Off = 524288;                   // flagsH2 [503][256] u32
constexpr size_t kH1ROff = 1048576;                  // h1 recs [503][256][256B]
constexpr size_t kRecBytes = 256;                    // 32 b x 4 units f16
constexpr size_t kH2ROff = kH1ROff + kSlots * 256 * kRecBytes;  // + 32.96MB
// LDS: h1 stage [32][1032] f16 | h2 stage same | zone 6*16*17 f32
constexpr int kStageRow = 1032;                      // f16 per b-row (pad 8)
constexpr int kH2Lds = kB * kStageRow;               // f16 index 33024
constexpr int kZoneBytes = 6 * 16 * 17 * 4;          // 6528
constexpr int kLdsBytes = 2 * kB * kStageRow * 2 + kZoneBytes;  // 138624
}

__device__ __forceinline__ float sigmoid_f(float x) {
  return __builtin_amdgcn_rcpf(1.f + __expf(-x));
}
__device__ __forceinline__ float tanh_f(float x) {
  return 1.f - 2.f * __builtin_amdgcn_rcpf(1.f + __expf(2.f * x));
}
__device__ __forceinline__ f16x8 load8(const float* p) {
  f16x8 r;
#pragma unroll
  for (int j = 0; j < 8; ++j) r[j] = (f16)p[j];
  return r;
}

__global__ void __launch_bounds__(256, 1) lstm_init_kernel(char* ws) {
  const int gid = blockIdx.x * 256 + threadIdx.x;     // 32768 threads
  unsigned* f1 = (unsigned*)(ws + kFH1Off);
  unsigned* f2 = (unsigned*)(ws + kFH2Off);
  const int nflags = (int)(kSlots * 256);             // 128768 per array
  for (int i = gid; i < nflags; i += 32768) {
    const unsigned v = (i < 256) ? 1u : 0u;           // slot 0 pre-ready
    f1[i] = v;
    f2[i] = v;
  }
  // zero slot-0 records (64 KB each)
  u64* r1 = (u64*)(ws + kH1ROff);
  u64* r2 = (u64*)(ws + kH2ROff);
  if (gid < 8192) { r1[gid] = 0ull; r2[gid] = 0ull; }
}

__global__ void __launch_bounds__(NTHR, 1) __attribute__((amdgpu_waves_per_eu(2)))
lstm_mfma_kernel(const float* __restrict__ x,
                 const float* __restrict__ Wih0, const float* __restrict__ Whh0,
                 const float* __restrict__ bih0, const float* __restrict__ bhh0,
                 const float* __restrict__ Wih1, const float* __restrict__ Whh1,
                 const float* __restrict__ bih1, const float* __restrict__ bhh1,
                 const float* __restrict__ Wfc, const float* __restrict__ bfc,
                 float* __restrict__ out, char* __restrict__ ws) {
  const int tid = threadIdx.x;
  const int bk = blockIdx.x;
  const int w = tid >> 6;                 // wave 0..7
  const int lane = tid & 63;
  const int m = lane & 15;                // A row / B col / D col
  const int kg = lane >> 4;               // k-group 0..3 (k = kg*8 + j)
  const int q = m >> 2, g = m & 3;        // A-row -> (unit-in-tile, gate)
  const int U0 = bk * 4;                  // owned unit base (both layers)

  unsigned* fH1 = (unsigned*)(ws + kFH1Off);
  unsigned* fH2 = (unsigned*)(ws + kFH2Off);
  extern __shared__ f16 lds[];
  float* zone = (float*)((char*)lds + 2 * kB * kStageRow * 2);  // 6*272 f32

  // ---- one-time A-fragment (weight) preload, f16 in VGPRs ----
  // A[m][k]: m = lane&15, k = kc*32 + (lane>>4)*8 + j
  f16x8 wL0[5], wL1[8], wFC[4];
#pragma unroll
  for (int i = 0; i < 4; ++i)             // L0 rec chunks (K 0..1023 of Whh0)
    wL0[i] = load8(Whh0 + (size_t)(g * kH + U0 + q) * kH + (w + 8 * i) * 32 + kg * 8);
  wL0[4] = load8(Wih0 + (size_t)(g * kH + U0 + q) * kI + w * 32 + kg * 8);
#pragma unroll
  for (int i = 0; i < 4; ++i)             // L1 input chunks (Wih1, K=h1)
    wL1[i] = load8(Wih1 + (size_t)(g * kH + U0 + q) * kH + (w + 8 * i) * 32 + kg * 8);
#pragma unroll
  for (int i = 4; i < 8; ++i)             // L1 rec chunks (Whh1, K=h2)
    wL1[i] = load8(Whh1 + (size_t)(g * kH + U0 + q) * kH + (w + 8 * (i - 4)) * 32 + kg * 8);
#pragma unroll
  for (int i = 0; i < 4; ++i) {           // FC rows: only m<2 valid (o=bk*2+m)
    f16x8 v = load8(Wfc + (size_t)(bk * 2 + (m < 2 ? m : 0)) * kH + (w + 8 * i) * 32 + kg * 8);
    if (m >= 2) {
#pragma unroll
      for (int j = 0; j < 8; ++j) v[j] = (f16)0.f;
    }
    wFC[i] = v;
  }
  // biases for finalize mapping: lane (b = lane>>1, p = lane&1, units 2p+s)
  const int pb = lane & 1;
  float biasL0[2][4], biasL1[2][4];
#pragma unroll
  for (int s = 0; s < 2; ++s) {
#pragma unroll
    for (int j = 0; j < 4; ++j) {
      const int uq = U0 + 2 * pb + s;
      biasL0[s][j] = bih0[j * kH + uq] + bhh0[j * kH + uq];
      biasL1[s][j] = bih1[j * kH + uq] + bhh1[j * kH + uq];
    }
  }
  const float bfc0 = bfc[bk * 2], bfc1 = bfc[bk * 2 + 1];
  float cL0[2] = {0.f, 0.f}, cL1[2] = {0.f, 0.f};  // c-state per (unit 2p+s)

  for (int r = 1; r <= kRounds; ++r) {
    // ---- S0: zones from previous round's finalize are free now
    __syncthreads();
    for (int i = tid; i < 6 * 272; i += NTHR) zone[i] = 0.f;

    // ---- stage: 1 thread : 1 record. waves 0-3 -> h1[r-1], waves 4-7 ->
    //      h2[r-2]. Poll ready flag (relaxed, sc1), then copy 256B -> LDS.
    {
      const int t = tid & 255;
      const bool isH1 = (tid < 256);
      const int rr = isH1 ? (r - 1) : (r >= 2 ? r - 2 : 0);
      unsigned* fp = (isH1 ? fH1 : fH2) + (size_t)rr * 256 + t;
      while (!__hip_atomic_load(fp, __ATOMIC_RELAXED, __HIP_MEMORY_SCOPE_AGENT))
        __builtin_amdgcn_s_sleep(1);
      asm volatile("" ::: "memory");      // order record loads after poll
      const char* rec = ws + (isH1 ? kH1ROff : kH2ROff) +
                        ((size_t)rr * 256 + t) * kRecBytes;
      f16* dst = lds + (isH1 ? 0 : kH2Lds) + t * 4;
      u64 v[32];
#pragma unroll
      for (int j = 0; j < 32; ++j)
        v[j] = __hip_atomic_load((const u64*)(rec + j * 8), __ATOMIC_RELAXED,
                                 __HIP_MEMORY_SCOPE_AGENT);
#pragma unroll
      for (int j = 0; j < 32; ++j)
        *(u64*)(dst + (size_t)j * kStageRow) = v[j];   // row b=j, cols t*4..+3
    }
    __syncthreads();                      // S1: stage + zone-zero complete

    // ================= L0: D = Whh0 @ h1[r-1] + Wih0 @ x[r-1] ==============
    {
      f32x4 a0 = {0.f, 0.f, 0.f, 0.f}, a1 = {0.f, 0.f, 0.f, 0.f};
#pragma unroll
      for (int i = 0; i < 4; ++i) {
        const int k = (w + 8 * i) * 32 + kg * 8;
        f16x8 b0 = *(const f16x8*)(lds + m * kStageRow + k);
        f16x8 b1 = *(const f16x8*)(lds + (16 + m) * kStageRow + k);
        a0 = __builtin_amdgcn_mfma_f32_16x16x32_f16(wL0[i], b0, a0, 0, 0, 0);
        a1 = __builtin_amdgcn_mfma_f32_16x16x32_f16(wL0[i], b1, a1, 0, 0, 0);
      }
      {  // x chunk: K' = w*32 .. w*32+31 of I=256
        const int kp = w * 32 + kg * 8;
        const float* xp0 = x + ((size_t)m * kT + (r - 1)) * kI + kp;
        f16x8 b0 = load8(xp0);
        f16x8 b1 = load8(xp0 + (size_t)16 * kT * kI);
        a0 = __builtin_amdgcn_mfma_f32_16x16x32_f16(wL0[4], b0, a0, 0, 0, 0);
        a1 = __builtin_amdgcn_mfma_f32_16x16x32_f16(wL0[4], b1, a1, 0, 0, 0);
      }
#pragma unroll
      for (int j = 0; j < 4; ++j) {
        atomicAdd(&zone[0 * 272 + (kg * 4 + j) * 17 + m], a0[j]);
        atomicAdd(&zone[1 * 272 + (kg * 4 + j) * 17 + m], a1[j]);
      }
    }
    __syncthreads();                      // S2: L0 zones complete

    // ---- wave 0: L0 finalize -> h1[r] record + ready flag (EARLY POST,
    //      before L1/FC -> off the inter-round critical path)
    if (w == 0) {
      const int b = lane >> 1, p = lane & 1;
      const float* z = zone + (b >> 4) * 272;
      const int col = b & 15;
      f16 hv[2];
#pragma unroll
      for (int s = 0; s < 2; ++s) {
        const int q4 = (2 * p + s) * 4;
        const float pi = z[(q4 + 0) * 17 + col] + biasL0[s][0];
        const float pf = z[(q4 + 1) * 17 + col] + biasL0[s][1];
        const float pg = z[(q4 + 2) * 17 + col] + biasL0[s][2];
        const float po = z[(q4 + 3) * 17 + col] + biasL0[s][3];
        float cc = cL0[s];
        cc = sigmoid_f(pf) * cc + sigmoid_f(pi) * tanh_f(pg);
        cL0[s] = cc;
        hv[s] = (f16)(sigmoid_f(po) * tanh_f(cc));
      }
      unsigned pk;
      __builtin_memcpy(&pk, hv, 4);
      __hip_atomic_store(
          (unsigned*)(ws + kH1ROff + ((size_t)r * 256 + bk) * kRecBytes +
                      b * 8 + p * 4),
          pk, __ATOMIC_RELAXED, __HIP_MEMORY_SCOPE_AGENT);
      if (lane == 0)
        __hip_atomic_store(fH1 + (size_t)r * 256 + bk, 1u, __ATOMIC_RELEASE,
                           __HIP_MEMORY_SCOPE_AGENT);
    }

    // ================= L1: D = Wih1 @ h1[r-1] + Whh1 @ h2[r-2] =============
    {
      f32x4 a0 = {0.f, 0.f, 0.f, 0.f}, a1 = {0.f, 0.f, 0.f, 0.f};
#pragma unroll
      for (int i = 0; i < 4; ++i) {
        const int k = (w + 8 * i) * 32 + kg * 8;
        f16x8 b0 = *(const f16x8*)(lds + m * kStageRow + k);
        f16x8 b1 = *(const f16x8*)(lds + (16 + m) * kStageRow + k);
        a0 = __builtin_amdgcn_mfma_f32_16x16x32_f16(wL1[i], b0, a0, 0, 0, 0);
        a1 = __builtin_amdgcn_mfma_f32_16x16x32_f16(wL1[i], b1, a1, 0, 0, 0);
      }
#pragma unroll
      for (int i = 4; i < 8; ++i) {
        const int k = (w + 8 * (i - 4)) * 32 + kg * 8;
        f16x8 b0 = *(const f16x8*)(lds + kH2Lds + m * kStageRow + k);
        f16x8 b1 = *(const f16x8*)(lds + kH2Lds + (16 + m) * kStageRow + k);
        a0 = __builtin_amdgcn_mfma_f32_16x16x32_f16(wL1[i], b0, a0, 0, 0, 0);
        a1 = __builtin_amdgcn_mfma_f32_16x16x32_f16(wL1[i], b1, a1, 0, 0, 0);
      }
#pragma unroll
      for (int j = 0; j < 4; ++j) {
        atomicAdd(&zone[2 * 272 + (kg * 4 + j) * 17 + m], a0[j]);
        atomicAdd(&zone[3 * 272 + (kg * 4 + j) * 17 + m], a1[j]);
      }
    }
    // ---- FC: D = Wfc @ h2[r-2]   (rows 0,1 valid; rest zero weights)
    {
      f32x4 a0 = {0.f, 0.f, 0.f, 0.f}, a1 = {0.f, 0.f, 0.f, 0.f};
#pragma unroll
      for (int i = 0; i < 4; ++i) {
        const int k = (w + 8 * i) * 32 + kg * 8;
        f16x8 b0 = *(const f16x8*)(lds + kH2Lds + m * kStageRow + k);
        f16x8 b1 = *(const f16x8*)(lds + kH2Lds + (16 + m) * kStageRow + k);
        a0 = __builtin_amdgcn_mfma_f32_16x16x32_f16(wFC[i], b0, a0, 0, 0, 0);
        a1 = __builtin_amdgcn_mfma_f32_16x16x32_f16(wFC[i], b1, a1, 0, 0, 0);
      }
#pragma unroll
      for (int j = 0; j < 2; ++j) {       // only rows 0,1 needed
        if (kg == 0) {
          atomicAdd(&zone[4 * 272 + j * 17 + m], a0[j]);
          atomicAdd(&zone[5 * 272 + j * 17 + m], a1[j]);
        }
      }
    }
    __syncthreads();                      // S3: L1/FC zones complete

    // ---- wave 1: L1 finalize -> h2[r-1] record + flag; wave 2: FC -> out
    if (w == 1 && r >= 2) {
      const int b = lane >> 1, p = lane & 1;
      const float* z = zone + (2 + (b >> 4)) * 272;
      const int col = b & 15;
      f16 hv[2];
#pragma unroll
      for (int s = 0; s < 2; ++s) {
        const int q4 = (2 * p + s) * 4;
        const float pi = z[(q4 + 0) * 17 + col] + biasL1[s][0];
        const float pf = z[(q4 + 1) * 17 + col] + biasL1[s][1];
        const float pg = z[(q4 + 2) * 17 + col] + biasL1[s][2];
        const float po = z[(q4 + 3) * 17 + col] + biasL1[s][3];
        float cc = cL1[s];
        cc = sigmoid_f(pf) * cc + sigmoid_f(pi) * tanh_f(pg);
        cL1[s] = cc;
        hv[s] = (f16)(sigmoid_f(po) * tanh_f(cc));
      }
      unsigned pk;
      __builtin_memcpy(&pk, hv, 4);
      __hip_atomic_store(
          (unsigned*)(ws + kH2ROff + ((size_t)(r - 1) * 256 + bk) * kRecBytes +
                      b * 8 + p * 4),
          pk, __ATOMIC_RELAXED, __HIP_MEMORY_SCOPE_AGENT);
      if (lane == 0)
        __hip_atomic_store(fH2 + (size_t)(r - 1) * 256 + bk, 1u,
                           __ATOMIC_RELEASE, __HIP_MEMORY_SCOPE_AGENT);
    } else if (w == 2 && r >= 3 && lane < 32) {  // FC -> out[:, r-3, :]
      const int b = lane;
      const float* z = zone + (4 + (lane >> 4)) * 272;
      const int c = lane & 15;
      float2 v;
      v.x = z[0 * 17 + c] + bfc0;
      v.y = z[1 * 17 + c] + bfc1;
      *(float2*)(out + ((size_t)b * kTR + (r - 3)) * kO + bk * 2) = v;
    }
  }
}

extern "C" void kernel_launch(void* const* d_in, const int* in_sizes, int n_in,
                              void* d_out, int out_size, void* d_ws,
                              size_t ws_size, hipStream_t stream) {
  const float* x    = (const float*)d_in[0];
  const float* Wih0 = (const float*)d_in[1];
  const float* Whh0 = (const float*)d_in[2];
  const float* bih0 = (const float*)d_in[3];
  const float* bhh0 = (const float*)d_in[4];
  const float* Wih1 = (const float*)d_in[5];
  const float* Whh1 = (const float*)d_in[6];
  const float* bih1 = (const float*)d_in[7];
  const float* bhh1 = (const float*)d_in[8];
  const float* Wfc  = (const float*)d_in[9];
  const float* bfc  = (const float*)d_in[10];
  float* out = (float*)d_out;
  char* ws   = (char*)d_ws;

  (void)hipFuncSetAttribute((const void*)lstm_mfma_kernel,
                            hipFuncAttributeMaxDynamicSharedMemorySize,
                            kLdsBytes);

  hipLaunchKernelGGL(lstm_init_kernel, dim3(128), dim3(256), 0, stream, ws);
  hipLaunchKernelGGL(lstm_mfma_kernel, dim3(NBLK), dim3(NTHR), kLdsBytes,
                     stream, x, Wih0, Whh0, bih0, bhh0, Wih1, Whh1, bih1,
                     bhh1, Wfc, bfc, out, ws);
}

// Round 4
// 12591.524 us; speedup vs baseline: 1.3404x; 1.3404x over previous
//
#include <hip/hip_runtime.h>
#include <cstdint>
#include <cstddef>

// ============================================================================
// Persistent fused 2-layer LSTM + FC for MI355X (gfx950) — Round 9:
// FENCE-FREE steady state. R8 post-mortem: per-thread flag polling (131072
// agent-scope spinners) re-created the fabric storm -> revert to R7b's
// aggregated barrier. R7b re-analysis: WRITE_SIZE 389MB vs ~100MB algorithmic
// => the per-round RELEASE emitted buffer_wbl2 (write back dirty L2) and the
// per-round ACQUIRE emitted buffer_inv (invalidate L2). Every round, every
// XCD: full dirty-L2 writeback (serialization + 290MB write amplification)
// and L2 invalidation (x/stage reads go LLC-cold). Fix:
//   - ALL cross-block traffic (h records, flags, gen) via RELAXED agent-scope
//     (sc1, LLC-direct) ops only. No release/acquire anywhere in the loop ->
//     no wbl2, no inv. Ordering: compiler's mandatory s_waitcnt vmcnt(0)
//     before s_barrier drains sc1 record stores to LLC (coherence point for
//     L2-bypass accesses) before tid0 posts the flag; flag->gen->stage-load
//     ordering is branch-data-dependent. R7b barrier shape minus fences.
//   - h slots flat [503][64KB]: producer wave stores ONE contiguous 256B
//     record (addr = slot + bk*256 + lane*4); consumer copy is linear
//     u64 loads at slot + tid*8 (+j*4KB) — perfectly coalesced both sides.
//   - LDS stage row 1032 -> 1034 f16 (bank stride 4 -> 5 dwords): conflict-
//     free stage writes AND B-frag ds_read_b128.
// x / weights / out stay L2-warm across all 502 rounds.
// MFMA layout, zone reduction, gate math, schedule unchanged from R7b.
// ============================================================================

#define NBLK 256
#define NTHR 512

typedef _Float16 f16;
typedef _Float16 f16x8 __attribute__((ext_vector_type(8)));
typedef float f32x4 __attribute__((ext_vector_type(4)));
typedef unsigned long long u64;

namespace {
constexpr int kB = 32, kT = 512, kI = 256, kH = 1024, kO = 512, kTR = 500;
constexpr int kRounds = 502;
constexpr size_t kSlots = 503;
constexpr size_t kSlotBytes = 65536;                 // 32 b x 1024 u x f16
// workspace layout (bytes)
constexpr size_t kH1Off = 4096;                      // flags in [0,4096)
constexpr size_t kH2Off = kH1Off + kSlots * kSlotBytes;
// LDS: h1 stage [32][1034] f16 | h2 stage same | zone 6*16*17 f32
constexpr int kStageRow = 1034;                      // f16 per b-row (pad 10)
constexpr int kH2Lds = kB * kStageRow;               // f16 index 33088
constexpr int kZoneBytes = 6 * 16 * 17 * 4;          // 6528
constexpr int kLdsBytes = 2 * kB * kStageRow * 2 + kZoneBytes;  // 138880
constexpr int kGen = 512;                            // generation word idx
}

__device__ __forceinline__ u64 ld_agent_u64(const void* p) {
  return __hip_atomic_load((const u64*)p, __ATOMIC_RELAXED,
                           __HIP_MEMORY_SCOPE_AGENT);
}
__device__ __forceinline__ void st_agent_u32(void* p, unsigned v) {
  __hip_atomic_store((unsigned*)p, v, __ATOMIC_RELAXED,
                     __HIP_MEMORY_SCOPE_AGENT);
}

// ---------------------------------------------------------------------------
// Aggregator grid barrier — ALL RELAXED (no wbl2 / no buffer_inv).
// Producers' record stores are drained to LLC by the compiler's vmcnt(0)
// before the first s_barrier; flag/gen chain is data-dependent.
__device__ __forceinline__ void grid_barrier(unsigned* flags, unsigned step) {
  __syncthreads();                        // drains all waves' sc1 stores
  const int tid = threadIdx.x;
  if (tid == 0)
    st_agent_u32(&flags[blockIdx.x], step);
  if (blockIdx.x == 0 && tid < 64) {
    const int l4 = tid << 2;
    bool done;
    do {
      unsigned ok = 1u;
#pragma unroll
      for (int k = 0; k < 4; ++k)
        ok &= (unsigned)(__hip_atomic_load(&flags[l4 + k], __ATOMIC_RELAXED,
                                           __HIP_MEMORY_SCOPE_AGENT) >= step);
      done = __all((int)ok);
      if (!done) __builtin_amdgcn_s_sleep(1);
    } while (!done);
    if (tid == 0)
      st_agent_u32(&flags[kGen], step);
  }
  if (tid == 0) {
    while (__hip_atomic_load(&flags[kGen], __ATOMIC_RELAXED,
                             __HIP_MEMORY_SCOPE_AGENT) < step)
      __builtin_amdgcn_s_sleep(1);
  }
  __syncthreads();
}

__device__ __forceinline__ float sigmoid_f(float x) {
  return __builtin_amdgcn_rcpf(1.f + __expf(-x));
}
__device__ __forceinline__ float tanh_f(float x) {
  return 1.f - 2.f * __builtin_amdgcn_rcpf(1.f + __expf(2.f * x));
}
__device__ __forceinline__ f16x8 load8(const float* p) {
  f16x8 r;
#pragma unroll
  for (int j = 0; j < 8; ++j) r[j] = (f16)p[j];
  return r;
}

__global__ void __launch_bounds__(256, 1) lstm_init_kernel(char* ws) {
  const int gid = blockIdx.x * 256 + threadIdx.x;     // 32768 threads
  unsigned* flags = (unsigned*)ws;
  if (gid < 1024) flags[gid] = 0u;
  // zero slot-0 of both h arrays (8192 u64 each)
  u64* r1 = (u64*)(ws + kH1Off);
  u64* r2 = (u64*)(ws + kH2Off);
  if (gid < 8192) { r1[gid] = 0ull; r2[gid] = 0ull; }
}

__global__ void __launch_bounds__(NTHR, 1) __attribute__((amdgpu_waves_per_eu(2)))
lstm_mfma_kernel(const float* __restrict__ x,
                 const float* __restrict__ Wih0, const float* __restrict__ Whh0,
                 const float* __restrict__ bih0, const float* __restrict__ bhh0,
                 const float* __restrict__ Wih1, const float* __restrict__ Whh1,
                 const float* __restrict__ bih1, const float* __restrict__ bhh1,
                 const float* __restrict__ Wfc, const float* __restrict__ bfc,
                 float* __restrict__ out, char* __restrict__ ws) {
  const int tid = threadIdx.x;
  const int bk = blockIdx.x;
  const int w = tid >> 6;                 // wave 0..7
  const int lane = tid & 63;
  const int m = lane & 15;                // A row / B col / D col
  const int kg = lane >> 4;               // k-group 0..3 (k = kg*8 + j)
  const int q = m >> 2, g = m & 3;        // A-row -> (unit-in-tile, gate)
  const int U0 = bk * 4;                  // owned unit base (both layers)

  unsigned* flags = (unsigned*)ws;
  extern __shared__ f16 lds[];
  float* zone = (float*)((char*)lds + 2 * kB * kStageRow * 2);  // 6*272 f32

  // ---- one-time A-fragment (weight) preload, f16 in VGPRs ----
  // A[m][k]: m = lane&15, k = kc*32 + (lane>>4)*8 + j
  f16x8 wL0[5], wL1[8], wFC[4];
#pragma unroll
  for (int i = 0; i < 4; ++i)             // L0 rec chunks (K 0..1023 of Whh0)
    wL0[i] = load8(Whh0 + (size_t)(g * kH + U0 + q) * kH + (w + 8 * i) * 32 + kg * 8);
  wL0[4] = load8(Wih0 + (size_t)(g * kH + U0 + q) * kI + w * 32 + kg * 8);
#pragma unroll
  for (int i = 0; i < 4; ++i)             // L1 input chunks (Wih1, K=h1)
    wL1[i] = load8(Wih1 + (size_t)(g * kH + U0 + q) * kH + (w + 8 * i) * 32 + kg * 8);
#pragma unroll
  for (int i = 4; i < 8; ++i)             // L1 rec chunks (Whh1, K=h2)
    wL1[i] = load8(Whh1 + (size_t)(g * kH + U0 + q) * kH + (w + 8 * (i - 4)) * 32 + kg * 8);
#pragma unroll
  for (int i = 0; i < 4; ++i) {           // FC rows: only m<2 valid (o=bk*2+m)
    f16x8 v = load8(Wfc + (size_t)(bk * 2 + (m < 2 ? m : 0)) * kH + (w + 8 * i) * 32 + kg * 8);
    if (m >= 2) {
#pragma unroll
      for (int j = 0; j < 8; ++j) v[j] = (f16)0.f;
    }
    wFC[i] = v;
  }
  // biases for finalize mapping: lane (b = lane>>1, p = lane&1, units 2p+s)
  const int pb = lane & 1;
  float biasL0[2][4], biasL1[2][4];
#pragma unroll
  for (int s = 0; s < 2; ++s) {
#pragma unroll
    for (int j = 0; j < 4; ++j) {
      const int uq = U0 + 2 * pb + s;
      biasL0[s][j] = bih0[j * kH + uq] + bhh0[j * kH + uq];
      biasL1[s][j] = bih1[j * kH + uq] + bhh1[j * kH + uq];
    }
  }
  const float bfc0 = bfc[bk * 2], bfc1 = bfc[bk * 2 + 1];
  float cL0[2] = {0.f, 0.f}, cL1[2] = {0.f, 0.f};  // c-state per (unit 2p+s)

  // stage-copy addressing (linear chunks): thread t owns chunks c = t + 512j
  // c -> (b = c&31 = t&31, rec = c>>5 = (t>>5)+16j); LDS f16 = b*Row + rec*4
  const int sb = tid & 31;
  const int sr = tid >> 5;                // 0..15
  f16* d1 = lds + sb * kStageRow + sr * 4;
  f16* d2 = lds + kH2Lds + sb * kStageRow + sr * 4;

  for (int r = 1; r <= kRounds; ++r) {
    // ---- zero reduction zone (overlaps staging load latency)
    for (int i = tid; i < 6 * 272; i += NTHR) zone[i] = 0.f;
    // ---- stage h1[r-1], h2[max(r-2,0)]: linear coalesced sc1 u64 loads
    {
      const u64* s1 = (const u64*)(ws + kH1Off + (size_t)(r - 1) * kSlotBytes) + tid;
      const u64* s2 = (const u64*)(ws + kH2Off + (size_t)(r >= 2 ? r - 2 : 0) * kSlotBytes) + tid;
#pragma unroll
      for (int jj = 0; jj < 16; jj += 4) {
        u64 a[4], c4[4];
#pragma unroll
        for (int k2 = 0; k2 < 4; ++k2) {
          a[k2] = ld_agent_u64(s1 + (jj + k2) * NTHR);
          c4[k2] = ld_agent_u64(s2 + (jj + k2) * NTHR);
        }
#pragma unroll
        for (int k2 = 0; k2 < 4; ++k2) {
          *(u64*)(d1 + (jj + k2) * 64) = a[k2];      // rec += 16 per j-step
          *(u64*)(d2 + (jj + k2) * 64) = c4[k2];
        }
      }
    }
    __syncthreads();

    // ================= MFMA sections (K chunks w, w+8, ...) =================
    // ---- L0: D = Whh0 @ h1[r-1]  +  Wih0 @ x[r-1]
    {
      f32x4 a0 = {0.f, 0.f, 0.f, 0.f}, a1 = {0.f, 0.f, 0.f, 0.f};
#pragma unroll
      for (int i = 0; i < 4; ++i) {
        const int k = (w + 8 * i) * 32 + kg * 8;
        f16x8 b0 = *(const f16x8*)(lds + m * kStageRow + k);
        f16x8 b1 = *(const f16x8*)(lds + (16 + m) * kStageRow + k);
        a0 = __builtin_amdgcn_mfma_f32_16x16x32_f16(wL0[i], b0, a0, 0, 0, 0);
        a1 = __builtin_amdgcn_mfma_f32_16x16x32_f16(wL0[i], b1, a1, 0, 0, 0);
      }
      {  // x chunk: K' = w*32 .. w*32+31 of I=256
        const int kp = w * 32 + kg * 8;
        const float* xp0 = x + ((size_t)m * kT + (r - 1)) * kI + kp;
        f16x8 b0 = load8(xp0);
        f16x8 b1 = load8(xp0 + (size_t)16 * kT * kI);
        a0 = __builtin_amdgcn_mfma_f32_16x16x32_f16(wL0[4], b0, a0, 0, 0, 0);
        a1 = __builtin_amdgcn_mfma_f32_16x16x32_f16(wL0[4], b1, a1, 0, 0, 0);
      }
#pragma unroll
      for (int j = 0; j < 4; ++j) {
        atomicAdd(&zone[0 * 272 + (kg * 4 + j) * 17 + m], a0[j]);
        atomicAdd(&zone[1 * 272 + (kg * 4 + j) * 17 + m], a1[j]);
      }
    }
    // ---- L1: D = Wih1 @ h1[r-1]  +  Whh1 @ h2[r-2]
    {
      f32x4 a0 = {0.f, 0.f, 0.f, 0.f}, a1 = {0.f, 0.f, 0.f, 0.f};
#pragma unroll
      for (int i = 0; i < 4; ++i) {
        const int k = (w + 8 * i) * 32 + kg * 8;
        f16x8 b0 = *(const f16x8*)(lds + m * kStageRow + k);
        f16x8 b1 = *(const f16x8*)(lds + (16 + m) * kStageRow + k);
        a0 = __builtin_amdgcn_mfma_f32_16x16x32_f16(wL1[i], b0, a0, 0, 0, 0);
        a1 = __builtin_amdgcn_mfma_f32_16x16x32_f16(wL1[i], b1, a1, 0, 0, 0);
      }
#pragma unroll
      for (int i = 4; i < 8; ++i) {
        const int k = (w + 8 * (i - 4)) * 32 + kg * 8;
        f16x8 b0 = *(const f16x8*)(lds + kH2Lds + m * kStageRow + k);
        f16x8 b1 = *(const f16x8*)(lds + kH2Lds + (16 + m) * kStageRow + k);
        a0 = __builtin_amdgcn_mfma_f32_16x16x32_f16(wL1[i], b0, a0, 0, 0, 0);
        a1 = __builtin_amdgcn_mfma_f32_16x16x32_f16(wL1[i], b1, a1, 0, 0, 0);
      }
#pragma unroll
      for (int j = 0; j < 4; ++j) {
        atomicAdd(&zone[2 * 272 + (kg * 4 + j) * 17 + m], a0[j]);
        atomicAdd(&zone[3 * 272 + (kg * 4 + j) * 17 + m], a1[j]);
      }
    }
    // ---- FC: D = Wfc @ h2[r-2]   (rows 0,1 valid; rest zero weights)
    {
      f32x4 a0 = {0.f, 0.f, 0.f, 0.f}, a1 = {0.f, 0.f, 0.f, 0.f};
#pragma unroll
      for (int i = 0; i < 4; ++i) {
        const int k = (w + 8 * i) * 32 + kg * 8;
        f16x8 b0 = *(const f16x8*)(lds + kH2Lds + m * kStageRow + k);
        f16x8 b1 = *(const f16x8*)(lds + kH2Lds + (16 + m) * kStageRow + k);
        a0 = __builtin_amdgcn_mfma_f32_16x16x32_f16(wFC[i], b0, a0, 0, 0, 0);
        a1 = __builtin_amdgcn_mfma_f32_16x16x32_f16(wFC[i], b1, a1, 0, 0, 0);
      }
#pragma unroll
      for (int j = 0; j < 2; ++j) {       // only rows 0,1 needed
        if (kg == 0) {
          atomicAdd(&zone[4 * 272 + j * 17 + m], a0[j]);
          atomicAdd(&zone[5 * 272 + j * 17 + m], a1[j]);
        }
      }
    }
    __syncthreads();

    // ================= finalize (waves 0/1/2) =================
    // lane = b*2+p: batch b = lane>>1, unit pair {2p, 2p+1}. Record store is
    // contiguous: slot + bk*256 + lane*4 (one coalesced 256B wave store).
    if (w == 0) {                          // L0 gate math -> h1[r]
      const int b = lane >> 1, p = lane & 1;
      const float* z = zone + (b >> 4) * 272;
      const int col = b & 15;
      f16 hv[2];
#pragma unroll
      for (int s = 0; s < 2; ++s) {
        const int q4 = (2 * p + s) * 4;
        const float pi = z[(q4 + 0) * 17 + col] + biasL0[s][0];
        const float pf = z[(q4 + 1) * 17 + col] + biasL0[s][1];
        const float pg = z[(q4 + 2) * 17 + col] + biasL0[s][2];
        const float po = z[(q4 + 3) * 17 + col] + biasL0[s][3];
        float cc = cL0[s];
        cc = sigmoid_f(pf) * cc + sigmoid_f(pi) * tanh_f(pg);
        cL0[s] = cc;
        hv[s] = (f16)(sigmoid_f(po) * tanh_f(cc));
      }
      unsigned pk;
      __builtin_memcpy(&pk, hv, 4);
      st_agent_u32(ws + kH1Off + (size_t)r * kSlotBytes + bk * 256 + lane * 4,
                   pk);
    } else if (w == 1 && r >= 2) {         // L1 gate math -> h2[r-1]
      const int b = lane >> 1, p = lane & 1;
      const float* z = zone + (2 + (b >> 4)) * 272;
      const int col = b & 15;
      f16 hv[2];
#pragma unroll
      for (int s = 0; s < 2; ++s) {
        const int q4 = (2 * p + s) * 4;
        const float pi = z[(q4 + 0) * 17 + col] + biasL1[s][0];
        const float pf = z[(q4 + 1) * 17 + col] + biasL1[s][1];
        const float pg = z[(q4 + 2) * 17 + col] + biasL1[s][2];
        const float po = z[(q4 + 3) * 17 + col] + biasL1[s][3];
        float cc = cL1[s];
        cc = sigmoid_f(pf) * cc + sigmoid_f(pi) * tanh_f(pg);
        cL1[s] = cc;
        hv[s] = (f16)(sigmoid_f(po) * tanh_f(cc));
      }
      unsigned pk;
      __builtin_memcpy(&pk, hv, 4);
      st_agent_u32(ws + kH2Off + (size_t)(r - 1) * kSlotBytes + bk * 256 +
                       lane * 4,
                   pk);
    } else if (w == 2 && r >= 3 && lane < 32) {  // FC -> out[:, r-3, :]
      const int b = lane;
      const float* z = zone + (4 + (lane >> 4)) * 272;
      const int c = lane & 15;
      float2 v;
      v.x = z[0 * 17 + c] + bfc0;
      v.y = z[1 * 17 + c] + bfc1;
      *(float2*)(out + ((size_t)b * kTR + (r - 3)) * kO + bk * 2) = v;
    }
    grid_barrier(flags, (unsigned)r);
  }
}

extern "C" void kernel_launch(void* const* d_in, const int* in_sizes, int n_in,
                              void* d_out, int out_size, void* d_ws,
                              size_t ws_size, hipStream_t stream) {
  const float* x    = (const float*)d_in[0];
  const float* Wih0 = (const float*)d_in[1];
  const float* Whh0 = (const float*)d_in[2];
  const float* bih0 = (const float*)d_in[3];
  const float* bhh0 = (const float*)d_in[4];
  const float* Wih1 = (const float*)d_in[5];
  const float* Whh1 = (const float*)d_in[6];
  const float* bih1 = (const float*)d_in[7];
  const float* bhh1 = (const float*)d_in[8];
  const float* Wfc  = (const float*)d_in[9];
  const float* bfc  = (const float*)d_in[10];
  float* out = (float*)d_out;
  char* ws   = (char*)d_ws;

  (void)hipFuncSetAttribute((const void*)lstm_mfma_kernel,
                            hipFuncAttributeMaxDynamicSharedMemorySize,
                            kLdsBytes);

  hipLaunchKernelGGL(lstm_init_kernel, dim3(128), dim3(256), 0, stream, ws);
  hipLaunchKernelGGL(lstm_mfma_kernel, dim3(NBLK), dim3(NTHR), kLdsBytes,
                     stream, x, Wih0, Whh0, bih0, bhh0, Wih1, Whh1, bih1,
                     bhh1, Wfc, bfc, out, ws);
}

// Round 5
// 8666.397 us; speedup vs baseline: 1.9475x; 1.4529x over previous
//
#include <hip/hip_runtime.h>
#include <cstdint>
#include <cstddef>

// ============================================================================
// Persistent fused 2-layer LSTM + FC for MI355X (gfx950) — Round 10:
// SPLIT-HALF DATAFLOW. R9 post-mortem: fence removal confirmed minor
// (WRITE 389->196MB), sc1 stage reads regressed (+3.8us/round) => stage
// broadcast + 256-block sync convergence dominate the ~21us round. Changes:
//   1. Chip split into 2 independent halves by BATCH (recurrence is
//      per-batch-independent). half = bk&1 -> disjoint XCD sets under
//      round-robin dispatch. 128 blocks/half, 16 batches, 8 units/block
//      (M=16: one B-tile, two A-tiles a0/a1). Sync scope halves; halves
//      slip independently (straggler decoupling); broadcast volume/block
//      halves (32KB h1 + 32KB h2).
//   2. Stage loads are PLAIN CACHEABLE f16x8 (L2-shared within XCD), with
//      NO per-round fence/inv: every consumer address is read exactly once,
//      strictly after the producer's sc1 (LLC-direct) store, ordered by the
//      relaxed flag barrier; no L2 prefetcher exists to fabricate stale
//      lines. (R7b's per-block inv was destroying exactly this sharing.)
//   3. All cross-block ops stay RELAXED agent-scope (no wbl2/inv anywhere).
// Padded LDS rows (1034 f16, 5-bank stride) kept from R9 (conflicts 94M->4M).
// Schedule r=1..502, gate order i,f,g,o, zone reduction: unchanged.
// ============================================================================

#define NBLK 256
#define NTHR 512

typedef _Float16 f16;
typedef _Float16 f16x8 __attribute__((ext_vector_type(8)));
typedef float f32x4 __attribute__((ext_vector_type(4)));
typedef unsigned long long u64;

namespace {
constexpr int kB = 32, kT = 512, kI = 256, kH = 1024, kO = 512, kTR = 500;
constexpr int kRounds = 502;
constexpr size_t kSlots = 503;
constexpr size_t kHalfSlot = 32768;                  // 16 b x 1024 u x f16
// workspace layout (bytes)
constexpr size_t kH1Off = 8192;                      // flags in [0,8192)
constexpr size_t kH2Off = kH1Off + kSlots * 2 * kHalfSlot;
// LDS: h1 stage [16][1034] f16 | h2 stage same | zone 5*16*17 f32
constexpr int kStageRow = 1034;                      // f16 per b-row (pad 10)
constexpr int kH2Lds = 16 * kStageRow;               // f16 index 16544
constexpr int kZoneF = 5 * 16 * 17;                  // 1360 f32
constexpr int kLdsBytes = 2 * kH2Lds * 2 + kZoneF * 4;  // 71616
}

__device__ __forceinline__ unsigned ld_agent_u32(const unsigned* p) {
  return __hip_atomic_load(p, __ATOMIC_RELAXED, __HIP_MEMORY_SCOPE_AGENT);
}
__device__ __forceinline__ void st_agent_u32(void* p, unsigned v) {
  __hip_atomic_store((unsigned*)p, v, __ATOMIC_RELAXED,
                     __HIP_MEMORY_SCOPE_AGENT);
}

// Per-half aggregator barrier, all relaxed. 128 flags/half; sweeper = bh==0.
__device__ __forceinline__ void half_barrier(unsigned* f, int bh,
                                             unsigned step) {
  __syncthreads();                        // drains each wave's sc1 stores
  const int tid = threadIdx.x;
  if (tid == 0) st_agent_u32(&f[bh], step);
  if (bh == 0 && tid < 64) {
    const int l2 = tid << 1;
    bool done;
    do {
      unsigned ok = (unsigned)(ld_agent_u32(&f[l2]) >= step) &
                    (unsigned)(ld_agent_u32(&f[l2 + 1]) >= step);
      done = __all((int)ok);
      if (!done) __builtin_amdgcn_s_sleep(1);
    } while (!done);
    if (tid == 0) st_agent_u32(&f[512], step);
  }
  if (tid == 0) {
    while (ld_agent_u32(&f[512]) < step) __builtin_amdgcn_s_sleep(1);
  }
  __syncthreads();
}

__device__ __forceinline__ float sigmoid_f(float x) {
  return __builtin_amdgcn_rcpf(1.f + __expf(-x));
}
__device__ __forceinline__ float tanh_f(float x) {
  return 1.f - 2.f * __builtin_amdgcn_rcpf(1.f + __expf(2.f * x));
}
__device__ __forceinline__ f16x8 load8(const float* p) {
  f16x8 r;
#pragma unroll
  for (int j = 0; j < 8; ++j) r[j] = (f16)p[j];
  return r;
}

__global__ void __launch_bounds__(256, 1) lstm_init_kernel(char* ws) {
  const int gid = blockIdx.x * 256 + threadIdx.x;     // 32768 threads
  unsigned* flags = (unsigned*)ws;
  if (gid < 2048) flags[gid] = 0u;
  // zero slot 0 (both halves) of h1 and h2: 64KB each = 8192 u64
  u64* r1 = (u64*)(ws + kH1Off);
  u64* r2 = (u64*)(ws + kH2Off);
  if (gid < 8192) { r1[gid] = 0ull; r2[gid] = 0ull; }
}

__global__ void __launch_bounds__(NTHR, 1) __attribute__((amdgpu_waves_per_eu(2)))
lstm_mfma_kernel(const float* __restrict__ x,
                 const float* __restrict__ Wih0, const float* __restrict__ Whh0,
                 const float* __restrict__ bih0, const float* __restrict__ bhh0,
                 const float* __restrict__ Wih1, const float* __restrict__ Whh1,
                 const float* __restrict__ bih1, const float* __restrict__ bhh1,
                 const float* __restrict__ Wfc, const float* __restrict__ bfc,
                 float* __restrict__ out, char* __restrict__ ws) {
  const int tid = threadIdx.x;
  const int bk = blockIdx.x;
  const int half = bk & 1;                // batch half: rows half*16..+15
  const int bh = bk >> 1;                 // block-in-half 0..127
  const int w = tid >> 6;                 // wave 0..7
  const int lane = tid & 63;
  const int m = lane & 15;                // A row / B col (batch) / D col
  const int kg = lane >> 4;               // k-group 0..3
  const int q = m >> 2, g = m & 3;        // A-row -> (unit-in-tile, gate)
  const int U0 = bh * 8;                  // owned unit base (both layers)

  unsigned* fl = (unsigned*)ws + (size_t)half * 1024;  // 128 flags + gen@512
  extern __shared__ f16 lds[];
  float* zone = (float*)((char*)lds + 2 * kH2Lds * 2);  // 5*272 f32

  // ---- one-time A-fragment (weight) preload, f16 in VGPRs ----
  // A[m][k]: m = lane&15, k = kc*32 + kg*8 + j. Tile0 = units U0+q,
  // tile1 = units U0+4+q (same gate g).
  f16x8 wA0[4], wA1[4], wI0[4], wI1[4], wR0[4], wR1[4], wF[4], wX0, wX1;
#pragma unroll
  for (int i = 0; i < 4; ++i) {
    const size_t kc = (size_t)(w + 8 * i) * 32 + kg * 8;
    wA0[i] = load8(Whh0 + (size_t)(g * kH + U0 + q) * kH + kc);
    wA1[i] = load8(Whh0 + (size_t)(g * kH + U0 + 4 + q) * kH + kc);
    wI0[i] = load8(Wih1 + (size_t)(g * kH + U0 + q) * kH + kc);
    wI1[i] = load8(Wih1 + (size_t)(g * kH + U0 + 4 + q) * kH + kc);
    wR0[i] = load8(Whh1 + (size_t)(g * kH + U0 + q) * kH + kc);
    wR1[i] = load8(Whh1 + (size_t)(g * kH + U0 + 4 + q) * kH + kc);
  }
  wX0 = load8(Wih0 + (size_t)(g * kH + U0 + q) * kI + w * 32 + kg * 8);
  wX1 = load8(Wih0 + (size_t)(g * kH + U0 + 4 + q) * kI + w * 32 + kg * 8);
#pragma unroll
  for (int i = 0; i < 4; ++i) {           // FC rows: m<4 valid (o = bh*4+m)
    f16x8 v = load8(Wfc + (size_t)(bh * 4 + (m < 4 ? m : 0)) * kH +
                    (size_t)(w + 8 * i) * 32 + kg * 8);
    if (m >= 4) {
#pragma unroll
      for (int j = 0; j < 8; ++j) v[j] = (f16)0.f;
    }
    wF[i] = v;
  }
  // biases for finalize: lane -> (b = lane>>2, p = lane&3), units U0+2p+s
  const int pb = lane & 3;
  float biasL0[2][4], biasL1[2][4];
#pragma unroll
  for (int s = 0; s < 2; ++s) {
#pragma unroll
    for (int j = 0; j < 4; ++j) {
      const int uq = U0 + 2 * pb + s;
      biasL0[s][j] = bih0[j * kH + uq] + bhh0[j * kH + uq];
      biasL1[s][j] = bih1[j * kH + uq] + bhh1[j * kH + uq];
    }
  }
  const float bfc_l = bfc[bh * 4 + (lane & 3)];
  float cL0[2] = {0.f, 0.f}, cL1[2] = {0.f, 0.f};

  // stage addressing: 16B chunk i = tid + 512j -> rec = i>>4, b = i&15 =
  // tid&15 (const), LDS col = rec*8. Global is perfectly linear.
  f16* d1 = lds + (tid & 15) * kStageRow + (tid >> 4) * 8;
  f16* d2 = d1 + kH2Lds;

  for (int r = 1; r <= kRounds; ++r) {
    // ---- zero reduction zone (overlaps staging load latency)
    for (int i = tid; i < kZoneF; i += NTHR) zone[i] = 0.f;
    // ---- stage h1[r-1], h2[max(r-2,0)] (own half): plain cached 16B loads
    {
      const char* s1 =
          ws + kH1Off + ((size_t)(r - 1) * 2 + half) * kHalfSlot;
      const char* s2 =
          ws + kH2Off + ((size_t)(r >= 2 ? r - 2 : 0) * 2 + half) * kHalfSlot;
      f16x8 a[4], c4[4];
#pragma unroll
      for (int j = 0; j < 4; ++j) {
        a[j] = *(const f16x8*)(s1 + ((size_t)tid + 512 * j) * 16);
        c4[j] = *(const f16x8*)(s2 + ((size_t)tid + 512 * j) * 16);
      }
#pragma unroll
      for (int j = 0; j < 4; ++j) {
        *(f16x8*)(d1 + (size_t)j * 256) = a[j];
        *(f16x8*)(d2 + (size_t)j * 256) = c4[j];
      }
    }
    __syncthreads();

    // ================= MFMA sections (K chunks w, w+8, ...) =================
    // ---- L0: D = Whh0 @ h1[r-1] + Wih0 @ x[r-1]   (2 A-tiles, 1 B-tile)
    {
      f32x4 a0 = {0.f, 0.f, 0.f, 0.f}, a1 = {0.f, 0.f, 0.f, 0.f};
#pragma unroll
      for (int i = 0; i < 4; ++i) {
        const int k = (w + 8 * i) * 32 + kg * 8;
        f16x8 bf = *(const f16x8*)(lds + m * kStageRow + k);
        a0 = __builtin_amdgcn_mfma_f32_16x16x32_f16(wA0[i], bf, a0, 0, 0, 0);
        a1 = __builtin_amdgcn_mfma_f32_16x16x32_f16(wA1[i], bf, a1, 0, 0, 0);
      }
      {  // x chunk: K' = w*32 .. w*32+31 of I=256
        const int kp = w * 32 + kg * 8;
        f16x8 bf =
            load8(x + ((size_t)(half * 16 + m) * kT + (r - 1)) * kI + kp);
        a0 = __builtin_amdgcn_mfma_f32_16x16x32_f16(wX0, bf, a0, 0, 0, 0);
        a1 = __builtin_amdgcn_mfma_f32_16x16x32_f16(wX1, bf, a1, 0, 0, 0);
      }
#pragma unroll
      for (int j = 0; j < 4; ++j) {
        atomicAdd(&zone[0 * 272 + (kg * 4 + j) * 17 + m], a0[j]);
        atomicAdd(&zone[1 * 272 + (kg * 4 + j) * 17 + m], a1[j]);
      }
    }
    // ---- L1: D = Wih1 @ h1[r-1] + Whh1 @ h2[r-2]
    {
      f32x4 a2 = {0.f, 0.f, 0.f, 0.f}, a3 = {0.f, 0.f, 0.f, 0.f};
#pragma unroll
      for (int i = 0; i < 4; ++i) {
        const int k = (w + 8 * i) * 32 + kg * 8;
        f16x8 bf = *(const f16x8*)(lds + m * kStageRow + k);
        a2 = __builtin_amdgcn_mfma_f32_16x16x32_f16(wI0[i], bf, a2, 0, 0, 0);
        a3 = __builtin_amdgcn_mfma_f32_16x16x32_f16(wI1[i], bf, a3, 0, 0, 0);
      }
#pragma unroll
      for (int i = 0; i < 4; ++i) {
        const int k = (w + 8 * i) * 32 + kg * 8;
        f16x8 bf = *(const f16x8*)(lds + kH2Lds + m * kStageRow + k);
        a2 = __builtin_amdgcn_mfma_f32_16x16x32_f16(wR0[i], bf, a2, 0, 0, 0);
        a3 = __builtin_amdgcn_mfma_f32_16x16x32_f16(wR1[i], bf, a3, 0, 0, 0);
      }
#pragma unroll
      for (int j = 0; j < 4; ++j) {
        atomicAdd(&zone[2 * 272 + (kg * 4 + j) * 17 + m], a2[j]);
        atomicAdd(&zone[3 * 272 + (kg * 4 + j) * 17 + m], a3[j]);
      }
    }
    // ---- FC: D = Wfc @ h2[r-2]   (rows 0..3 valid -> o = bh*4+row)
    {
      f32x4 a4 = {0.f, 0.f, 0.f, 0.f};
#pragma unroll
      for (int i = 0; i < 4; ++i) {
        const int k = (w + 8 * i) * 32 + kg * 8;
        f16x8 bf = *(const f16x8*)(lds + kH2Lds + m * kStageRow + k);
        a4 = __builtin_amdgcn_mfma_f32_16x16x32_f16(wF[i], bf, a4, 0, 0, 0);
      }
      if (kg == 0) {
#pragma unroll
        for (int j = 0; j < 4; ++j)
          atomicAdd(&zone[4 * 272 + j * 17 + m], a4[j]);
      }
    }
    __syncthreads();

    // ================= finalize (waves 0/1/2) =================
    // lane -> (b = lane>>2, p = lane&3): units {2p, 2p+1} of this block.
    // Record store: half-slot + bh*256 + b*16 + p*4 (contiguous 256B/wave).
    if (w == 0) {                          // L0 gate math -> h1[r]
      const int b = lane >> 2, p = lane & 3;
      f16 hv[2];
#pragma unroll
      for (int s = 0; s < 2; ++s) {
        const int u = 2 * p + s;
        const float* z = zone + (u >> 2) * 272;
        const int rq = (u & 3) * 4;
        const float pi = z[(rq + 0) * 17 + b] + biasL0[s][0];
        const float pf = z[(rq + 1) * 17 + b] + biasL0[s][1];
        const float pg = z[(rq + 2) * 17 + b] + biasL0[s][2];
        const float po = z[(rq + 3) * 17 + b] + biasL0[s][3];
        float cc = cL0[s];
        cc = sigmoid_f(pf) * cc + sigmoid_f(pi) * tanh_f(pg);
        cL0[s] = cc;
        hv[s] = (f16)(sigmoid_f(po) * tanh_f(cc));
      }
      unsigned pk;
      __builtin_memcpy(&pk, hv, 4);
      st_agent_u32(ws + kH1Off + ((size_t)r * 2 + half) * kHalfSlot +
                       bh * 256 + b * 16 + p * 4,
                   pk);
    } else if (w == 1 && r >= 2) {         // L1 gate math -> h2[r-1]
      const int b = lane >> 2, p = lane & 3;
      f16 hv[2];
#pragma unroll
      for (int s = 0; s < 2; ++s) {
        const int u = 2 * p + s;
        const float* z = zone + (2 + (u >> 2)) * 272;
        const int rq = (u & 3) * 4;
        const float pi = z[(rq + 0) * 17 + b] + biasL1[s][0];
        const float pf = z[(rq + 1) * 17 + b] + biasL1[s][1];
        const float pg = z[(rq + 2) * 17 + b] + biasL1[s][2];
        const float po = z[(rq + 3) * 17 + b] + biasL1[s][3];
        float cc = cL1[s];
        cc = sigmoid_f(pf) * cc + sigmoid_f(pi) * tanh_f(pg);
        cL1[s] = cc;
        hv[s] = (f16)(sigmoid_f(po) * tanh_f(cc));
      }
      unsigned pk;
      __builtin_memcpy(&pk, hv, 4);
      st_agent_u32(ws + kH2Off + ((size_t)(r - 1) * 2 + half) * kHalfSlot +
                       bh * 256 + b * 16 + p * 4,
                   pk);
    } else if (w == 2 && r >= 3) {         // FC -> out[:, r-3, bh*4..+3]
      const int b = lane >> 2, oo = lane & 3;
      const float v = zone[4 * 272 + oo * 17 + b] + bfc_l;
      out[((size_t)(half * 16 + b) * kTR + (r - 3)) * kO + bh * 4 + oo] = v;
    }
    half_barrier(fl, bh, (unsigned)r);
  }
}

extern "C" void kernel_launch(void* const* d_in, const int* in_sizes, int n_in,
                              void* d_out, int out_size, void* d_ws,
                              size_t ws_size, hipStream_t stream) {
  const float* x    = (const float*)d_in[0];
  const float* Wih0 = (const float*)d_in[1];
  const float* Whh0 = (const float*)d_in[2];
  const float* bih0 = (const float*)d_in[3];
  const float* bhh0 = (const float*)d_in[4];
  const float* Wih1 = (const float*)d_in[5];
  const float* Whh1 = (const float*)d_in[6];
  const float* bih1 = (const float*)d_in[7];
  const float* bhh1 = (const float*)d_in[8];
  const float* Wfc  = (const float*)d_in[9];
  const float* bfc  = (const float*)d_in[10];
  float* out = (float*)d_out;
  char* ws   = (char*)d_ws;

  (void)hipFuncSetAttribute((const void*)lstm_mfma_kernel,
                            hipFuncAttributeMaxDynamicSharedMemorySize,
                            kLdsBytes);

  hipLaunchKernelGGL(lstm_init_kernel, dim3(128), dim3(256), 0, stream, ws);
  hipLaunchKernelGGL(lstm_mfma_kernel, dim3(NBLK), dim3(NTHR), kLdsBytes,
                     stream, x, Wih0, Whh0, bih0, bhh0, Wih1, Whh1, bih1,
                     bhh1, Wfc, bfc, out, ws);
}